// Round 1
// baseline (968.066 us; speedup 1.0000x reference)
//
#include <hip/hip_runtime.h>

#define S_LEN 2048
#define NB 16

typedef float f32x4 __attribute__((ext_vector_type(4)));
typedef int   i32x4 __attribute__((ext_vector_type(4)));
typedef int   i32x2 __attribute__((ext_vector_type(2)));

__device__ __forceinline__ float rl63(float x){
  return __uint_as_float(__builtin_amdgcn_readlane(__float_as_uint(x), 63));
}
template<int CTRL>
__device__ __forceinline__ float dppadd(float x){
  int y = __builtin_amdgcn_update_dpp(0, __float_as_int(x), CTRL, 0xf, 0xf, false);
  return x + __int_as_float(y);
}
// wave64 sum, result valid in lane 63 (rocPRIM pattern)
__device__ __forceinline__ float wsum64(float x){
  x = dppadd<0x111>(x);  // row_shr:1
  x = dppadd<0x112>(x);  // row_shr:2
  x = dppadd<0x114>(x);  // row_shr:4
  x = dppadd<0x118>(x);  // row_shr:8
  x = dppadd<0x142>(x);  // row_bcast:15
  x = dppadd<0x143>(x);  // row_bcast:31
  return x;
}
__device__ __forceinline__ unsigned bf16rne(float f){
  unsigned u = __float_as_uint(f);
  return (u + 0x7fffu + ((u >> 16) & 1u)) >> 16;
}

// ---------------- W_out -> bf16 hi/lo split ----------------
__global__ __launch_bounds__(256) void wprep_kernel(const float* __restrict__ W,
                                                    ushort* __restrict__ whi,
                                                    ushort* __restrict__ wlo)
{
  int i = blockIdx.x * 1024 + threadIdx.x * 4;  // 4096*64 = 262144 elems, 256 blocks
  f32x4 v = *(const f32x4*)(W + i);
#pragma unroll
  for (int j = 0; j < 4; ++j){
    unsigned hb = bf16rne(v[j]);
    float hf = __uint_as_float(hb << 16);
    unsigned lb = bf16rne(v[j] - hf);
    whi[i + j] = (ushort)hb;
    wlo[i + j] = (ushort)lb;
  }
}

// ---------------- sequential scan: one wave per batch ----------------
__global__ __launch_bounds__(64) void scan_kernel(
    const int* __restrict__ ids, const float* __restrict__ emb,
    const float* __restrict__ Wg, const float* __restrict__ bg,
    const float* __restrict__ dlg, const float* __restrict__ esc,
    ushort* __restrict__ chi, ushort* __restrict__ clo)
{
  const int b = blockIdx.x;
  const int l = threadIdx.x;          // 0..63 ; lanes 0-31 = h_r[d], 32-63 = h_i[d]
  const int d = l & 31;
  const int head = d >> 3;
  const float es  = esc[0];
  const float dk  = 1.f / (1.f + __expf(-dlg[head]));   // decay (sigmoid)
  const float bgl = bg[head];
  const float wg0 = Wg[l*4+0], wg1 = Wg[l*4+1], wg2 = Wg[l*4+2], wg3 = Wg[l*4+3];
  const int* idr = ids + b * S_LEN;
  ushort* ch = chi + (size_t)b * S_LEN * 64 + l;
  ushort* cl = clo + (size_t)b * S_LEN * 64 + l;

  const float PHI_F    = 1.6180339887498949f;
  const float TWOPI_F  = 6.283185307179586f;
  const float INV2PI_F = 0.15915494309189535f;

  float h = 0.f, m = 0.f;
  int id0 = idr[0];
  float w  = emb[id0*64 + d];
  float bp = emb[id0*64 + 32 + d];
  float invw = __builtin_amdgcn_rcpf(1.f + __builtin_fabsf(w));

  for (int s = 0; s < S_LEN; ++s){
    // prefetch next emb row (off critical path)
    int sn_i = (s + 1 < S_LEN) ? (s + 1) : s;
    int idn = idr[sn_i];
    float wn  = emb[idn*64 + d];
    float bpn = emb[idn*64 + 32 + d];

    float tp = (float)s * PHI_F;
    float th = __builtin_fmaf(h, invw, bp) + tp;       // matches (h/wav + b) + tp order
    // exact-ish mod 2pi (fma-cancellation; fixups cover floor off-by-one)
    float q = __builtin_floorf(th * INV2PI_F);
    float r = __builtin_fmaf(-q, TWOPI_F, th);
    r = (r < 0.f) ? (r + TWOPI_F) : r;
    r = (r >= TWOPI_F) ? (r - TWOPI_F) : r;
    float rev = r * INV2PI_F;                          // [0,1) revolutions
    float sn, cs;
    asm("v_sin_f32 %0, %1" : "=v"(sn) : "v"(rev));
    asm("v_cos_f32 %0, %1" : "=v"(cs) : "v"(rev));
    // exchange (sin,cos) with the partner half (r<->i)
    float os = __shfl_xor(sn, 32, 64);
    float oc = __shfl_xor(cs, 32, 64);
    float hn = (l < 32) ? (cs*oc - sn*os)    // h_r = c_r*c_i - s_r*s_i
                        : (oc*sn + os*cs);   // h_i = c_r*s_i + s_r*c_i
    h = hn;

    // gate = sigmoid(concat(h_r,h_i) @ W_gate + b_gate)  -- 4 wave reductions
    float g0 = wsum64(h * wg0);
    float g1 = wsum64(h * wg1);
    float g2 = wsum64(h * wg2);
    float g3 = wsum64(h * wg3);
    float z0 = rl63(g0), z1 = rl63(g1), z2 = rl63(g2), z3 = rl63(g3);
    float z = (head == 0) ? z0 : (head == 1) ? z1 : (head == 2) ? z2 : z3;
    z += bgl;
    float g = 1.f / (1.f + __expf(-z));
    m = __builtin_fmaf(dk, m, g * h);
    float outv = __builtin_fmaf(es, m, h);             // h + es*m

    // split to bf16 hi/lo for the MFMA projection
    unsigned hb = bf16rne(outv);
    float hf = __uint_as_float(hb << 16);
    unsigned lb = bf16rne(outv - hf);
    ch[(size_t)s * 64] = (ushort)hb;
    cl[(size_t)s * 64] = (ushort)lb;

    w = wn; bp = bpn;
    invw = __builtin_amdgcn_rcpf(1.f + __builtin_fabsf(wn));
  }
}

// ---------------- projection: [32768,64] x [4096,64]^T, split-bf16 MFMA ----------------
// tile 128 rows x 128 cols, 4 waves (2x2 quadrants of 64x64), K=64 fully resident.
// LDS tiles [128][64] bf16, 16B-chunk swizzle: chunk16 ^= (row&7); 8B frag reads use
// chunk8 ^= ((row&7)<<1) which is the same permutation.
__global__ __launch_bounds__(256) void gemm_kernel(
    const ushort* __restrict__ chi, const ushort* __restrict__ clo,
    const ushort* __restrict__ whi, const ushort* __restrict__ wlo,
    const float* __restrict__ bout, float* __restrict__ out)
{
  __shared__ char lds[65536];  // A_hi | A_lo | W_hi | W_lo, 16KB each
  const int row0 = blockIdx.y * 128;
  const int v0   = blockIdx.x * 128;
  const int t = threadIdx.x;

  {
    const char* s0 = (const char*)(chi) + (size_t)row0 * 128;
    const char* s1 = (const char*)(clo) + (size_t)row0 * 128;
    const char* s2 = (const char*)(whi) + (size_t)v0 * 128;
    const char* s3 = (const char*)(wlo) + (size_t)v0 * 128;
    const char* srcs[4] = {s0, s1, s2, s3};
#pragma unroll
    for (int a2 = 0; a2 < 4; ++a2){
      char* dst = lds + a2 * 16384;
      const char* src = srcs[a2];
#pragma unroll
      for (int i = 0; i < 4; ++i){
        int id = t + 256 * i;          // 1024 chunks of 16B
        int r = id >> 3, c = id & 7;
        i32x4 v = *(const i32x4*)(src + r*128 + c*16);
        *(i32x4*)(dst + r*128 + ((c ^ (r & 7)) * 16)) = v;
      }
    }
  }
  __syncthreads();

  const int lane = t & 63;
  const int wid  = t >> 6;
  const int wr = (wid >> 1) * 64;
  const int wc = (wid & 1) * 64;
  const int lr = lane & 15;
  const int lk = lane >> 4;           // k-group 0..3

  f32x4 acc[4][4];
#pragma unroll
  for (int m = 0; m < 4; ++m)
#pragma unroll
    for (int n = 0; n < 4; ++n) acc[m][n] = (f32x4){0.f, 0.f, 0.f, 0.f};

  // A fragments (hi & lo), classic 16x16x16 layout: lane holds A[lr][ks*16+lk*4 .. +3]
  i32x2 afr[2][4][4];
#pragma unroll
  for (int hf = 0; hf < 2; ++hf){
    const char* Ab = lds + hf * 16384;
#pragma unroll
    for (int m = 0; m < 4; ++m){
      int row = wr + m*16 + lr;
      const char* rp = Ab + row * 128;
      int sw = (row & 7) << 1;
#pragma unroll
      for (int ks = 0; ks < 4; ++ks){
        int c8 = (ks*4 + lk) ^ sw;
        afr[hf][m][ks] = *(const i32x2*)(rp + c8 * 8);
      }
    }
  }
#pragma unroll
  for (int wh = 0; wh < 2; ++wh){
    const char* Bb = lds + 32768 + wh * 16384;
    i32x2 bfr[4][4];
#pragma unroll
    for (int n = 0; n < 4; ++n){
      int row = wc + n*16 + lr;
      const char* rp = Bb + row * 128;
      int sw = (row & 7) << 1;
#pragma unroll
      for (int ks = 0; ks < 4; ++ks){
        int c8 = (ks*4 + lk) ^ sw;
        bfr[n][ks] = *(const i32x2*)(rp + c8 * 8);
      }
    }
#pragma unroll
    for (int hf = 0; hf < 2; ++hf)
#pragma unroll
      for (int m = 0; m < 4; ++m)
#pragma unroll
        for (int n = 0; n < 4; ++n)
#pragma unroll
          for (int ks = 0; ks < 4; ++ks)
            asm("v_mfma_f32_16x16x16_bf16 %0, %1, %2, %0"
                : "+v"(acc[m][n]) : "v"(afr[hf][m][ks]), "v"(bfr[n][ks]));
  }

  // epilogue: C/D layout col = lane&15, row = (lane>>4)*4 + reg
#pragma unroll
  for (int n = 0; n < 4; ++n){
    float bias = bout[v0 + wc + n*16 + lr];
#pragma unroll
    for (int m = 0; m < 4; ++m){
      int gr = row0 + wr + m*16 + lk*4;
      float* op = out + (size_t)gr * 4096 + (v0 + wc + n*16 + lr);
#pragma unroll
      for (int rg = 0; rg < 4; ++rg){
        op[(size_t)rg * 4096] = acc[m][n][rg] + bias;
      }
    }
  }
}

extern "C" void kernel_launch(void* const* d_in, const int* in_sizes, int n_in,
                              void* d_out, int out_size, void* d_ws, size_t ws_size,
                              hipStream_t stream)
{
  const int*   ids  = (const int*)  d_in[0];
  const float* emb  = (const float*)d_in[1];
  const float* Wout = (const float*)d_in[2];
  const float* bout = (const float*)d_in[3];
  const float* Wg   = (const float*)d_in[4];
  const float* bg   = (const float*)d_in[5];
  const float* dlg  = (const float*)d_in[6];
  const float* esc  = (const float*)d_in[7];
  float* out = (float*)d_out;
  char* ws = (char*)d_ws;
  // ws layout: c_hi 4MB | c_lo 4MB | w_hi 512KB | w_lo 512KB  (9MB total)
  ushort* chi = (ushort*)(ws);
  ushort* clo = (ushort*)(ws + 4u*1024u*1024u);
  ushort* whi = (ushort*)(ws + 8u*1024u*1024u);
  ushort* wlo = (ushort*)(ws + 8u*1024u*1024u + 512u*1024u);

  wprep_kernel<<<dim3(256), dim3(256), 0, stream>>>(Wout, whi, wlo);
  scan_kernel<<<dim3(NB), dim3(64), 0, stream>>>(ids, emb, Wg, bg, dlg, esc, chi, clo);
  gemm_kernel<<<dim3(32, 256), dim3(256), 0, stream>>>(chi, clo, whi, wlo, bout, out);
}

// Round 3
// 220.418 us; speedup vs baseline: 4.3920x; 4.3920x over previous
//
#include <hip/hip_runtime.h>

#define S_LEN 2048

typedef float f32x4 __attribute__((ext_vector_type(4)));
typedef int   i32x4 __attribute__((ext_vector_type(4)));
typedef int   i32x2 __attribute__((ext_vector_type(2)));

__device__ __forceinline__ float sin2pi(float rev){ float r; asm("v_sin_f32 %0, %1":"=v"(r):"v"(rev)); return r; }
__device__ __forceinline__ float cos2pi(float rev){ float r; asm("v_cos_f32 %0, %1":"=v"(r):"v"(rev)); return r; }

template<int CTRL>
__device__ __forceinline__ float dppadd(float x){
  int y = __builtin_amdgcn_update_dpp(0, __float_as_int(x), CTRL, 0xf, 0xf, false);
  return x + __int_as_float(y);
}
// sum within each 32-lane half; totals end in lane 31 (half 0) and lane 63 (half 1)
__device__ __forceinline__ float wsum32(float x){
  x = dppadd<0x111>(x);  // row_shr:1
  x = dppadd<0x112>(x);  // row_shr:2
  x = dppadd<0x114>(x);  // row_shr:4
  x = dppadd<0x118>(x);  // row_shr:8
  x = dppadd<0x142>(x);  // row_bcast:15
  return x;
}
// broadcast lane31 -> lanes 0..31 and lane63 -> lanes 32..63 (BitMode or=31)
__device__ __forceinline__ float bcast31(float x){
  return __int_as_float(__builtin_amdgcn_ds_swizzle(__float_as_int(x), 0x3E0));
}
__device__ __forceinline__ unsigned bf16rne(float f){
  unsigned u = __float_as_uint(f);
  return (u + 0x7fffu + ((u >> 16) & 1u)) >> 16;
}

// ---------------- W_out -> bf16 hi/lo split, K-permuted: k' = 2*d + di ----------------
// scan stores combs with out_r at k'=2d, out_i at k'=2d+1; W columns permuted identically,
// so the GEMM's K-dot is invariant.
__global__ __launch_bounds__(256) void wprep_kernel(const float* __restrict__ W,
                                                    ushort* __restrict__ whi,
                                                    ushort* __restrict__ wlo)
{
  int i = blockIdx.x * 256 + threadIdx.x;      // 262144 total
  int v = i >> 6, kp = i & 63;
  int d = kp >> 1, di = kp & 1;
  float x = W[v*64 + di*32 + d];
  unsigned hb = bf16rne(x);
  float hf = __uint_as_float(hb << 16);
  unsigned lb = bf16rne(x - hf);
  whi[i] = (ushort)hb;
  wlo[i] = (ushort)lb;
}

// ---------------- chunked speculative scan ----------------
// 16 chunks of 128 steps + 128-step warm-up (contraction ~e^-0.41/step -> bit-merge).
// 2 batches per wave (lanes 0-31 = batch A, lanes 32-63 = batch B).
// Each lane holds h_r[d], h_i[d], m_r[d], m_i[d] for its dim d — R1-exact step numerics.
__global__ __launch_bounds__(64) void scan_kernel(
    const int* __restrict__ ids, const float* __restrict__ emb,
    const float* __restrict__ Wg, const float* __restrict__ bg,
    const float* __restrict__ dlg, const float* __restrict__ esc,
    ushort* __restrict__ chi, ushort* __restrict__ clo)
{
  const int w  = blockIdx.x;        // 128 blocks x 1 wave
  const int c  = w >> 3;            // chunk 0..15
  const int bp = w & 7;             // batch pair
  const int l  = threadIdx.x;
  const int half = l >> 5;
  const int b  = bp*2 + half;
  const int d  = l & 31;
  const int hd = d >> 3;

  const float es  = esc[0];
  const float dk  = 1.f/(1.f + __expf(-dlg[hd]));
  const float bgl = bg[hd];
  const f32x4 wgr = *(const f32x4*)(Wg + d*4);        // W_gate rows for h_r[d]
  const f32x4 wgi = *(const f32x4*)(Wg + (32+d)*4);   // W_gate rows for h_i[d]
  const bool h0 = (hd==0), h1 = (hd==1), h2 = (hd==2);

  const int s0   = c*128;
  const int sw   = (c==0) ? 0 : (s0-128);
  const int send = s0 + 128;

  const int* idb = ids + b*S_LEN;
  const float* ef = emb;
  char* chp = (char*)chi + (size_t)(b*S_LEN + sw)*128 + d*4;
  char* clp = (char*)clo + (size_t)(b*S_LEN + sw)*128 + d*4;

  float hr = 0.f, hi = 0.f, mr = 0.f, mi = 0.f;

  const float PHI_F   = 1.6180339887498949f;
  const float TWOPI_F = 6.283185307179586f;
  const float INV2PI  = 0.15915494309189535f;

  auto clampi = [](int x){ return x > (S_LEN-4) ? (S_LEN-4) : x; };

  // ---- pipeline preload ----
  i32x4 qA = *(const i32x4*)(idb + sw);
  float wA[4], bA[4], wB[4], bB[4];
#pragma unroll
  for (int j=0;j<4;++j){ wA[j] = ef[qA[j]*64 + d]; bA[j] = ef[qA[j]*64 + 32 + d]; }
  i32x4 qn  = *(const i32x4*)(idb + clampi(sw+4));   // ids for steps sb+4..7
  i32x4 qn2 = *(const i32x4*)(idb + clampi(sw+8));   // ids for steps sb+8..11

  auto STEP = [&](int s, float wv, float bpv, bool st, char* pch, char* pcl){
    float invw = __builtin_amdgcn_rcpf(1.f + __builtin_fabsf(wv));
    float tp = (float)s * PHI_F;
    // th = (h/wav + b) + tp  (R1-exact rounding order)
    float thr = __builtin_fmaf(hr, invw, bpv) + tp;
    float thi = __builtin_fmaf(hi, invw, bpv) + tp;
    // R1-exact range reduction: floor + exact-cancel fma + fixups
    float qr = __builtin_floorf(thr * INV2PI);
    float rr = __builtin_fmaf(-qr, TWOPI_F, thr);
    rr = (rr < 0.f) ? (rr + TWOPI_F) : rr;
    rr = (rr >= TWOPI_F) ? (rr - TWOPI_F) : rr;
    float qi = __builtin_floorf(thi * INV2PI);
    float ri = __builtin_fmaf(-qi, TWOPI_F, thi);
    ri = (ri < 0.f) ? (ri + TWOPI_F) : ri;
    ri = (ri >= TWOPI_F) ? (ri - TWOPI_F) : ri;
    float sr = sin2pi(rr * INV2PI), cr = cos2pi(rr * INV2PI);
    float si = sin2pi(ri * INV2PI), ci = cos2pi(ri * INV2PI);
    float nhr = __builtin_fmaf(cr, ci, -(sr*si));   // c_r*c_i - s_r*s_i
    float nhi = __builtin_fmaf(cr, si,  sr*ci);     // c_r*s_i + s_r*c_i
    hr = nhr; hi = nhi;
    // gate partials for 4 heads
    float p0 = __builtin_fmaf(hr, wgr[0], hi*wgi[0]);
    float p1 = __builtin_fmaf(hr, wgr[1], hi*wgi[1]);
    float p2 = __builtin_fmaf(hr, wgr[2], hi*wgi[2]);
    float p3 = __builtin_fmaf(hr, wgr[3], hi*wgi[3]);
    float z0 = bcast31(wsum32(p0));
    float z1 = bcast31(wsum32(p1));
    float z2 = bcast31(wsum32(p2));
    float z3 = bcast31(wsum32(p3));
    float z  = h0 ? z0 : (h1 ? z1 : (h2 ? z2 : z3));
    float g  = 1.f / (1.f + __expf(-(z + bgl)));
    mr = __builtin_fmaf(dk, mr, g*hr);
    mi = __builtin_fmaf(dk, mi, g*hi);
    float orr = __builtin_fmaf(es, mr, hr);
    float oi  = __builtin_fmaf(es, mi, hi);
    unsigned hw_; asm("v_cvt_pk_bf16_f32 %0, %1, %2" : "=v"(hw_) : "v"(orr), "v"(oi));
    float hrf = __uint_as_float(hw_ << 16);
    float hif = __uint_as_float(hw_ & 0xffff0000u);
    float lr_ = orr - hrf, li_ = oi - hif;
    unsigned lw_; asm("v_cvt_pk_bf16_f32 %0, %1, %2" : "=v"(lw_) : "v"(lr_), "v"(li_));
    if (st){ *(unsigned*)pch = hw_; *(unsigned*)pcl = lw_; }
  };

  for (int sb = sw; sb < send; sb += 8){
    char* p0c = chp + (size_t)(sb - sw)*128;
    char* p0l = clp + (size_t)(sb - sw)*128;
    // phase 0: consume A (steps sb..sb+3); issue emb for sb+4..7 into B
#pragma unroll
    for (int j=0;j<4;++j){ wB[j] = ef[qn[j]*64 + d]; bB[j] = ef[qn[j]*64 + 32 + d]; }
    i32x4 qx = *(const i32x4*)(idb + clampi(sb+12));
    bool st = (sb >= s0);
#pragma unroll
    for (int j=0;j<4;++j) STEP(sb+j, wA[j], bA[j], st, p0c + j*128, p0l + j*128);
    // phase 1: consume B (steps sb+4..7); issue emb for sb+8..11 into A
#pragma unroll
    for (int j=0;j<4;++j){ wA[j] = ef[qn2[j]*64 + d]; bA[j] = ef[qn2[j]*64 + 32 + d]; }
    i32x4 qy = *(const i32x4*)(idb + clampi(sb+16));
#pragma unroll
    for (int j=0;j<4;++j) STEP(sb+4+j, wB[j], bB[j], st, p0c + 512 + j*128, p0l + 512 + j*128);
    qn = qx; qn2 = qy;
  }
}

// ---------------- projection: [32768,64] x [4096,64]^T, split-bf16 MFMA ----------------
__global__ __launch_bounds__(256) void gemm_kernel(
    const ushort* __restrict__ chi, const ushort* __restrict__ clo,
    const ushort* __restrict__ whi, const ushort* __restrict__ wlo,
    const float* __restrict__ bout, float* __restrict__ out)
{
  __shared__ char lds[65536];  // A_hi | A_lo | W_hi | W_lo, 16KB each
  const int row0 = blockIdx.y * 128;
  const int v0   = blockIdx.x * 128;
  const int t = threadIdx.x;

  {
    const char* s0 = (const char*)(chi) + (size_t)row0 * 128;
    const char* s1 = (const char*)(clo) + (size_t)row0 * 128;
    const char* s2 = (const char*)(whi) + (size_t)v0 * 128;
    const char* s3 = (const char*)(wlo) + (size_t)v0 * 128;
    const char* srcs[4] = {s0, s1, s2, s3};
#pragma unroll
    for (int a2 = 0; a2 < 4; ++a2){
      char* dst = lds + a2 * 16384;
      const char* src = srcs[a2];
#pragma unroll
      for (int i = 0; i < 4; ++i){
        int id = t + 256 * i;          // 1024 chunks of 16B
        int r = id >> 3, ccol = id & 7;
        i32x4 vv = *(const i32x4*)(src + r*128 + ccol*16);
        *(i32x4*)(dst + r*128 + ((ccol ^ (r & 7)) * 16)) = vv;
      }
    }
  }
  __syncthreads();

  const int lane = t & 63;
  const int wid  = t >> 6;
  const int wr = (wid >> 1) * 64;
  const int wc = (wid & 1) * 64;
  const int lr = lane & 15;
  const int lk = lane >> 4;           // k-group 0..3

  f32x4 acc[4][4];
#pragma unroll
  for (int m = 0; m < 4; ++m)
#pragma unroll
    for (int n = 0; n < 4; ++n) acc[m][n] = (f32x4){0.f, 0.f, 0.f, 0.f};

  i32x2 afr[2][4][4];
#pragma unroll
  for (int hf = 0; hf < 2; ++hf){
    const char* Ab = lds + hf * 16384;
#pragma unroll
    for (int m = 0; m < 4; ++m){
      int row = wr + m*16 + lr;
      const char* rp = Ab + row * 128;
      int sw = (row & 7) << 1;
#pragma unroll
      for (int ks = 0; ks < 4; ++ks){
        int c8 = (ks*4 + lk) ^ sw;
        afr[hf][m][ks] = *(const i32x2*)(rp + c8 * 8);
      }
    }
  }
#pragma unroll
  for (int wh = 0; wh < 2; ++wh){
    const char* Bb = lds + 32768 + wh * 16384;
    i32x2 bfr[4][4];
#pragma unroll
    for (int n = 0; n < 4; ++n){
      int row = wc + n*16 + lr;
      const char* rp = Bb + row * 128;
      int sw = (row & 7) << 1;
#pragma unroll
      for (int ks = 0; ks < 4; ++ks){
        int c8 = (ks*4 + lk) ^ sw;
        bfr[n][ks] = *(const i32x2*)(rp + c8 * 8);
      }
    }
#pragma unroll
    for (int hf = 0; hf < 2; ++hf)
#pragma unroll
      for (int m = 0; m < 4; ++m)
#pragma unroll
        for (int n = 0; n < 4; ++n)
#pragma unroll
          for (int ks = 0; ks < 4; ++ks)
            asm("v_mfma_f32_16x16x16_bf16 %0, %1, %2, %0"
                : "+v"(acc[m][n]) : "v"(afr[hf][m][ks]), "v"(bfr[n][ks]));
  }

  // epilogue: C/D layout col = lane&15, row = (lane>>4)*4 + reg
#pragma unroll
  for (int n = 0; n < 4; ++n){
    float bias = bout[v0 + wc + n*16 + lr];
#pragma unroll
    for (int m = 0; m < 4; ++m){
      int gr = row0 + wr + m*16 + lk*4;
      float* op = out + (size_t)gr * 4096 + (v0 + wc + n*16 + lr);
#pragma unroll
      for (int rg = 0; rg < 4; ++rg){
        op[(size_t)rg * 4096] = acc[m][n][rg] + bias;
      }
    }
  }
}

extern "C" void kernel_launch(void* const* d_in, const int* in_sizes, int n_in,
                              void* d_out, int out_size, void* d_ws, size_t ws_size,
                              hipStream_t stream)
{
  const int*   ids  = (const int*)  d_in[0];
  const float* emb  = (const float*)d_in[1];
  const float* Wout = (const float*)d_in[2];
  const float* bout = (const float*)d_in[3];
  const float* Wg   = (const float*)d_in[4];
  const float* bg   = (const float*)d_in[5];
  const float* dlg  = (const float*)d_in[6];
  const float* esc  = (const float*)d_in[7];
  float* out = (float*)d_out;
  char* ws = (char*)d_ws;
  // ws layout: c_hi 4MB | c_lo 4MB | w_hi 512KB | w_lo 512KB  (9MB total)
  ushort* chi = (ushort*)(ws);
  ushort* clo = (ushort*)(ws + 4u*1024u*1024u);
  ushort* whi = (ushort*)(ws + 8u*1024u*1024u);
  ushort* wlo = (ushort*)(ws + 8u*1024u*1024u + 512u*1024u);

  wprep_kernel<<<dim3(1024), dim3(256), 0, stream>>>(Wout, whi, wlo);
  scan_kernel<<<dim3(128), dim3(64), 0, stream>>>(ids, emb, Wg, bg, dlg, esc, chi, clo);
  gemm_kernel<<<dim3(32, 256), dim3(256), 0, stream>>>(chi, clo, whi, wlo, bout, out);
}

// Round 4
// 209.985 us; speedup vs baseline: 4.6102x; 1.0497x over previous
//
#include <hip/hip_runtime.h>

#define S_LEN 2048

typedef float f32x4 __attribute__((ext_vector_type(4)));
typedef float f32x2 __attribute__((ext_vector_type(2)));
typedef int   i32x4 __attribute__((ext_vector_type(4)));
typedef int   i32x2 __attribute__((ext_vector_type(2)));

__device__ __forceinline__ float sin2pi(float rev){ float r; asm("v_sin_f32 %0, %1":"=v"(r):"v"(rev)); return r; }
__device__ __forceinline__ float cos2pi(float rev){ float r; asm("v_cos_f32 %0, %1":"=v"(r):"v"(rev)); return r; }
template<int M>
__device__ __forceinline__ float swz(float x){
  return __int_as_float(__builtin_amdgcn_ds_swizzle(__float_as_int(x), M));
}
// 32-lane xor-butterfly sum (per 32-lane half independently); result in ALL lanes
__device__ __forceinline__ float bfly32(float x){
  x += swz<0x041F>(x);
  x += swz<0x081F>(x);
  x += swz<0x101F>(x);
  x += swz<0x201F>(x);
  x += swz<0x401F>(x);
  return x;
}

// ================= scan (blocks 0..127) + W-split prep (blocks 128..1151) =================
// scan: 16 chunks x 128 steps, 128-step warm-up (contraction ~e^-0.41/step), 2 batches/wave.
// 4-step groups, manually software-pipelined: HCHAIN(g+1) issued before GATE/M/STORE(g).
__global__ __launch_bounds__(64) void scan_kernel(
    const int* __restrict__ ids, const float* __restrict__ emb,
    const float* __restrict__ Wg, const float* __restrict__ bg,
    const float* __restrict__ dlg, const float* __restrict__ esc,
    ushort* __restrict__ chi, ushort* __restrict__ clo,
    const float* __restrict__ W32, ushort* __restrict__ whi, ushort* __restrict__ wlo)
{
  const int w = blockIdx.x;
  const int l = threadIdx.x;

  if (w >= 128){
    // ---- W_out -> bf16 hi/lo split, K-permuted k' = 2*d + di ----
    int i0 = (w - 128) * 256 + l * 4;          // 4 consecutive k' elements
    int v  = i0 >> 6;
    int t4 = (i0 & 63) >> 2;                   // kp = 4*t4 .. 4*t4+3
    f32x2 fa = *(const f32x2*)(W32 + v*64 + 2*t4);        // di=0 pair (d=2t4, 2t4+1)
    f32x2 fb = *(const f32x2*)(W32 + v*64 + 32 + 2*t4);   // di=1 pair
    unsigned h0_, h1_, l0_, l1_;
    asm("v_cvt_pk_bf16_f32 %0, %1, %2":"=v"(h0_):"v"(fa[0]),"v"(fb[0]));
    asm("v_cvt_pk_bf16_f32 %0, %1, %2":"=v"(h1_):"v"(fa[1]),"v"(fb[1]));
    float r00 = fa[0] - __uint_as_float(h0_ << 16);
    float r01 = fb[0] - __uint_as_float(h0_ & 0xffff0000u);
    float r10 = fa[1] - __uint_as_float(h1_ << 16);
    float r11 = fb[1] - __uint_as_float(h1_ & 0xffff0000u);
    asm("v_cvt_pk_bf16_f32 %0, %1, %2":"=v"(l0_):"v"(r00),"v"(r01));
    asm("v_cvt_pk_bf16_f32 %0, %1, %2":"=v"(l1_):"v"(r10),"v"(r11));
    *(i32x2*)(whi + i0) = (i32x2){(int)h0_, (int)h1_};
    *(i32x2*)(wlo + i0) = (i32x2){(int)l0_, (int)l1_};
    return;
  }

  // ---- scan ----
  const int c  = w >> 3;            // chunk 0..15
  const int bp = w & 7;             // batch pair
  const int half = l >> 5;
  const int b  = bp*2 + half;
  const int d  = l & 31;
  const int hd = d >> 3;

  const float es  = esc[0];
  const float dk  = 1.f/(1.f + __expf(-dlg[hd]));
  const float bgl = bg[hd];
  const f32x4 wgr = *(const f32x4*)(Wg + d*4);
  const f32x4 wgi = *(const f32x4*)(Wg + (32+d)*4);
  const bool hs0 = (hd==0), hs1 = (hd==1), hs2 = (hd==2);

  const int s0   = c*128;
  const int sw   = (c==0) ? 0 : (s0-128);
  const int send = s0 + 128;
  const int ngroups = (send - sw) >> 2;   // 32 (c==0) or 64

  const int* idb = ids + b*S_LEN;
  char* chp = (char*)chi + (size_t)(b*S_LEN + sw)*128 + d*4;
  char* clp = (char*)clo + (size_t)(b*S_LEN + sw)*128 + d*4;

  float hr = 0.f, hi = 0.f, mr = 0.f, mi = 0.f;

  const float PHI_F   = 1.6180339887498949f;
  const float TWOPI_F = 6.283185307179586f;
  const float INV2PI  = 0.15915494309189535f;

  auto clampi = [](int x){ return x > (S_LEN-4) ? (S_LEN-4) : x; };

  auto LOADE = [&](const i32x4& q, float (&wv)[4], float (&bv)[4]){
#pragma unroll
    for (int j=0;j<4;++j){ wv[j] = emb[q[j]*64 + d]; bv[j] = emb[q[j]*64 + 32 + d]; }
  };

  // R3-exact per-theta step numerics
  auto HCHAIN = [&](int sbase, const float (&wv)[4], const float (&bv)[4],
                    float (&hrj)[4], float (&hij)[4]){
#pragma unroll
    for (int j=0;j<4;++j){
      float invw = __builtin_amdgcn_rcpf(1.f + __builtin_fabsf(wv[j]));
      float tp = (float)(sbase + j) * PHI_F;
      float thr = __builtin_fmaf(hr, invw, bv[j]) + tp;
      float thi = __builtin_fmaf(hi, invw, bv[j]) + tp;
      float qr = __builtin_floorf(thr * INV2PI);
      float rr = __builtin_fmaf(-qr, TWOPI_F, thr);
      rr = (rr < 0.f) ? (rr + TWOPI_F) : rr;
      rr = (rr >= TWOPI_F) ? (rr - TWOPI_F) : rr;
      float qi = __builtin_floorf(thi * INV2PI);
      float ri = __builtin_fmaf(-qi, TWOPI_F, thi);
      ri = (ri < 0.f) ? (ri + TWOPI_F) : ri;
      ri = (ri >= TWOPI_F) ? (ri - TWOPI_F) : ri;
      float sr = sin2pi(rr * INV2PI), cr = cos2pi(rr * INV2PI);
      float si = sin2pi(ri * INV2PI), ci = cos2pi(ri * INV2PI);
      float nhr = __builtin_fmaf(cr, ci, -(sr*si));
      float nhi = __builtin_fmaf(cr, si,  sr*ci);
      hr = nhr; hi = nhi;
      hrj[j] = nhr; hij[j] = nhi;
    }
  };

  auto GATEG = [&](int g, const float (&hrj)[4], const float (&hij)[4]){
    float p[4][4];
#pragma unroll
    for (int j=0;j<4;++j){
#pragma unroll
      for (int k=0;k<4;++k)
        p[j][k] = __builtin_fmaf(hrj[j], wgr[k], hij[j]*wgi[k]);
    }
#pragma unroll
    for (int j=0;j<4;++j){
#pragma unroll
      for (int k=0;k<4;++k)
        p[j][k] = bfly32(p[j][k]);
    }
    bool st = (sw + 4*g) >= s0;
    char* pch = chp + (size_t)(4*g)*128;
    char* pcl = clp + (size_t)(4*g)*128;
#pragma unroll
    for (int j=0;j<4;++j){
      float z = hs0 ? p[j][0] : (hs1 ? p[j][1] : (hs2 ? p[j][2] : p[j][3]));
      float g_ = 1.f / (1.f + __expf(-(z + bgl)));
      mr = __builtin_fmaf(dk, mr, g_*hrj[j]);
      mi = __builtin_fmaf(dk, mi, g_*hij[j]);
      float orr = __builtin_fmaf(es, mr, hrj[j]);
      float oi  = __builtin_fmaf(es, mi, hij[j]);
      unsigned hw_; asm("v_cvt_pk_bf16_f32 %0, %1, %2" : "=v"(hw_) : "v"(orr), "v"(oi));
      float hrf = __uint_as_float(hw_ << 16);
      float hif = __uint_as_float(hw_ & 0xffff0000u);
      float lr_ = orr - hrf, li_ = oi - hif;
      unsigned lw_; asm("v_cvt_pk_bf16_f32 %0, %1, %2" : "=v"(lw_) : "v"(lr_), "v"(li_));
      if (st){ *(unsigned*)(pch + j*128) = hw_; *(unsigned*)(pcl + j*128) = lw_; }
    }
  };

  float wA[4], bA[4], wB[4], bB[4];
  float hA_r[4], hA_i[4], hB_r[4], hB_i[4];

  // prologue: groups 0,1 emb; ids for group 2; h-chain group 0
  i32x4 q0 = *(const i32x4*)(idb + sw);
  LOADE(q0, wA, bA);
  i32x4 q1 = *(const i32x4*)(idb + clampi(sw + 4));
  LOADE(q1, wB, bB);
  i32x4 qn = *(const i32x4*)(idb + clampi(sw + 8));
  HCHAIN(sw, wA, bA, hA_r, hA_i);

  const int ndbl = (ngroups - 1) >> 1;
  for (int i = 0; i < ndbl; ++i){
    int g = 2*i;
    // even phase: emb(g+2)->A, hchain(g+1) from B, gate(g) from A-h
    LOADE(qn, wA, bA);
    qn = *(const i32x4*)(idb + clampi(sw + 4*(g+3)));
    HCHAIN(sw + 4*(g+1), wB, bB, hB_r, hB_i);
    GATEG(g, hA_r, hA_i);
    // odd phase: emb(g+3)->B, hchain(g+2) from A, gate(g+1) from B-h
    LOADE(qn, wB, bB);
    qn = *(const i32x4*)(idb + clampi(sw + 4*(g+4)));
    HCHAIN(sw + 4*(g+2), wA, bA, hA_r, hA_i);
    GATEG(g+1, hB_r, hB_i);
  }
  // leftover: hchain(ngroups-1) from B, then final two gates
  {
    int g = ngroups - 2;            // = 2*ndbl (even)
    HCHAIN(sw + 4*(g+1), wB, bB, hB_r, hB_i);
    GATEG(g, hA_r, hA_i);
    GATEG(g+1, hB_r, hB_i);
  }
}

// ---------------- projection: [32768,64] x [4096,64]^T, split-bf16 MFMA (unchanged, validated) ----------------
__global__ __launch_bounds__(256) void gemm_kernel(
    const ushort* __restrict__ chi, const ushort* __restrict__ clo,
    const ushort* __restrict__ whi, const ushort* __restrict__ wlo,
    const float* __restrict__ bout, float* __restrict__ out)
{
  __shared__ char lds[65536];  // A_hi | A_lo | W_hi | W_lo, 16KB each
  const int row0 = blockIdx.y * 128;
  const int v0   = blockIdx.x * 128;
  const int t = threadIdx.x;

  {
    const char* s0 = (const char*)(chi) + (size_t)row0 * 128;
    const char* s1 = (const char*)(clo) + (size_t)row0 * 128;
    const char* s2 = (const char*)(whi) + (size_t)v0 * 128;
    const char* s3 = (const char*)(wlo) + (size_t)v0 * 128;
    const char* srcs[4] = {s0, s1, s2, s3};
#pragma unroll
    for (int a2 = 0; a2 < 4; ++a2){
      char* dst = lds + a2 * 16384;
      const char* src = srcs[a2];
#pragma unroll
      for (int i = 0; i < 4; ++i){
        int id = t + 256 * i;          // 1024 chunks of 16B
        int r = id >> 3, ccol = id & 7;
        i32x4 vv = *(const i32x4*)(src + r*128 + ccol*16);
        *(i32x4*)(dst + r*128 + ((ccol ^ (r & 7)) * 16)) = vv;
      }
    }
  }
  __syncthreads();

  const int lane = t & 63;
  const int wid  = t >> 6;
  const int wr = (wid >> 1) * 64;
  const int wc = (wid & 1) * 64;
  const int lr = lane & 15;
  const int lk = lane >> 4;           // k-group 0..3

  f32x4 acc[4][4];
#pragma unroll
  for (int m = 0; m < 4; ++m)
#pragma unroll
    for (int n = 0; n < 4; ++n) acc[m][n] = (f32x4){0.f, 0.f, 0.f, 0.f};

  i32x2 afr[2][4][4];
#pragma unroll
  for (int hf = 0; hf < 2; ++hf){
    const char* Ab = lds + hf * 16384;
#pragma unroll
    for (int m = 0; m < 4; ++m){
      int row = wr + m*16 + lr;
      const char* rp = Ab + row * 128;
      int sw = (row & 7) << 1;
#pragma unroll
      for (int ks = 0; ks < 4; ++ks){
        int c8 = (ks*4 + lk) ^ sw;
        afr[hf][m][ks] = *(const i32x2*)(rp + c8 * 8);
      }
    }
  }
#pragma unroll
  for (int wh = 0; wh < 2; ++wh){
    const char* Bb = lds + 32768 + wh * 16384;
    i32x2 bfr[4][4];
#pragma unroll
    for (int n = 0; n < 4; ++n){
      int row = wc + n*16 + lr;
      const char* rp = Bb + row * 128;
      int sw = (row & 7) << 1;
#pragma unroll
      for (int ks = 0; ks < 4; ++ks){
        int c8 = (ks*4 + lk) ^ sw;
        bfr[n][ks] = *(const i32x2*)(rp + c8 * 8);
      }
    }
#pragma unroll
    for (int hf = 0; hf < 2; ++hf)
#pragma unroll
      for (int m = 0; m < 4; ++m)
#pragma unroll
        for (int n = 0; n < 4; ++n)
#pragma unroll
          for (int ks = 0; ks < 4; ++ks)
            asm("v_mfma_f32_16x16x16_bf16 %0, %1, %2, %0"
                : "+v"(acc[m][n]) : "v"(afr[hf][m][ks]), "v"(bfr[n][ks]));
  }

  // epilogue: C/D layout col = lane&15, row = (lane>>4)*4 + reg
#pragma unroll
  for (int n = 0; n < 4; ++n){
    float bias = bout[v0 + wc + n*16 + lr];
#pragma unroll
    for (int m = 0; m < 4; ++m){
      int gr = row0 + wr + m*16 + lk*4;
      float* op = out + (size_t)gr * 4096 + (v0 + wc + n*16 + lr);
#pragma unroll
      for (int rg = 0; rg < 4; ++rg){
        op[(size_t)rg * 4096] = acc[m][n][rg] + bias;
      }
    }
  }
}

extern "C" void kernel_launch(void* const* d_in, const int* in_sizes, int n_in,
                              void* d_out, int out_size, void* d_ws, size_t ws_size,
                              hipStream_t stream)
{
  const int*   ids  = (const int*)  d_in[0];
  const float* emb  = (const float*)d_in[1];
  const float* Wout = (const float*)d_in[2];
  const float* bout = (const float*)d_in[3];
  const float* Wg   = (const float*)d_in[4];
  const float* bg   = (const float*)d_in[5];
  const float* dlg  = (const float*)d_in[6];
  const float* esc  = (const float*)d_in[7];
  float* out = (float*)d_out;
  char* ws = (char*)d_ws;
  // ws layout: c_hi 4MB | c_lo 4MB | w_hi 512KB | w_lo 512KB  (9MB total)
  ushort* chi = (ushort*)(ws);
  ushort* clo = (ushort*)(ws + 4u*1024u*1024u);
  ushort* whi = (ushort*)(ws + 8u*1024u*1024u);
  ushort* wlo = (ushort*)(ws + 8u*1024u*1024u + 512u*1024u);

  // blocks 0..127: scan (scheduled first = critical path); 128..1151: W split
  scan_kernel<<<dim3(1152), dim3(64), 0, stream>>>(ids, emb, Wg, bg, dlg, esc,
                                                   chi, clo, Wout, whi, wlo);
  gemm_kernel<<<dim3(32, 256), dim3(256), 0, stream>>>(chi, clo, whi, wlo, bout, out);
}

// Round 7
// 190.390 us; speedup vs baseline: 5.0847x; 1.1029x over previous
//
#include <hip/hip_runtime.h>

#define S_LEN 2048

typedef float f32x4 __attribute__((ext_vector_type(4)));
typedef float f32x2 __attribute__((ext_vector_type(2)));
typedef int   i32x4 __attribute__((ext_vector_type(4)));
typedef int   i32x2 __attribute__((ext_vector_type(2)));

__device__ __forceinline__ float sin2pi(float rev){ float r; asm("v_sin_f32 %0, %1":"=v"(r):"v"(rev)); return r; }
__device__ __forceinline__ float cos2pi(float rev){ float r; asm("v_cos_f32 %0, %1":"=v"(r):"v"(rev)); return r; }
__device__ __forceinline__ float fractf_(float x){ float r; asm("v_fract_f32 %0, %1":"=v"(r):"v"(x)); return r; }
template<int M>
__device__ __forceinline__ float swz(float x){
  return __int_as_float(__builtin_amdgcn_ds_swizzle(__float_as_int(x), M));
}
template<int CTRL>
__device__ __forceinline__ float dppmov(float x){
  return __int_as_float(__builtin_amdgcn_update_dpp(0, __float_as_int(x), CTRL, 0xf, 0xf, false));
}
// pair-sum across the 32-lane halves: result[l] = x[l] + x[l^32].
// Via __shfl_xor (ds_permute path — proven in R1). FP add is commutative, so
// partner lanes compute bit-identical sums.
__device__ __forceinline__ float psum64(float x){
  return x + __shfl_xor(x, 32, 64);
}

// lane layout (scan): comp = l>>5 (0:h_r, 1:h_i), d = ((l>>2)&7) | ((l&3)<<3) => head(d) = l&3
// K-permutation: comb element k'' = l  <->  concat index comp*32 + d. W columns permuted identically.

// ================= scan (blocks 0..255) + W-split prep (blocks 256..1279) =================
__global__ __launch_bounds__(64) void scan_kernel(
    const int* __restrict__ ids, const float* __restrict__ emb,
    const float* __restrict__ Wg, const float* __restrict__ bg,
    const float* __restrict__ dlg, const float* __restrict__ esc,
    ushort* __restrict__ chi, ushort* __restrict__ clo,
    const float* __restrict__ W32, ushort* __restrict__ whi, ushort* __restrict__ wlo)
{
  const int w = blockIdx.x;
  const int l = threadIdx.x;

  if (w >= 256){
    // ---- W_out -> bf16 hi/lo split with k'' lane permutation ----
    int i0 = (w - 256) * 256 + l * 4;          // 4 consecutive k'' elements
    int v  = i0 >> 6;
    int q  = (i0 & 63) >> 2;                   // k'' = 4q + jj
    int base = v*64 + (q >> 3)*32 + (q & 7);   // + 8*jj
    float x0 = W32[base], x1 = W32[base+8], x2 = W32[base+16], x3 = W32[base+24];
    unsigned hw01, hw23, lw01, lw23;
    asm("v_cvt_pk_bf16_f32 %0, %1, %2":"=v"(hw01):"v"(x0),"v"(x1));
    asm("v_cvt_pk_bf16_f32 %0, %1, %2":"=v"(hw23):"v"(x2),"v"(x3));
    float r0 = x0 - __uint_as_float(hw01 << 16);
    float r1 = x1 - __uint_as_float(hw01 & 0xffff0000u);
    float r2 = x2 - __uint_as_float(hw23 << 16);
    float r3 = x3 - __uint_as_float(hw23 & 0xffff0000u);
    asm("v_cvt_pk_bf16_f32 %0, %1, %2":"=v"(lw01):"v"(r0),"v"(r1));
    asm("v_cvt_pk_bf16_f32 %0, %1, %2":"=v"(lw23):"v"(r2),"v"(r3));
    *(i32x2*)(whi + i0) = (i32x2){(int)hw01, (int)hw23};
    *(i32x2*)(wlo + i0) = (i32x2){(int)lw01, (int)lw23};
    return;
  }

  // ---- scan: 16 chunks x 128 steps + 128-step warmup, 1 batch per wave ----
  const int c  = w >> 4;            // chunk 0..15
  const int b  = w & 15;            // batch
  const bool lo = (l < 32);
  const int d  = ((l >> 2) & 7) | ((l & 3) << 3);
  const bool b0 = (l & 1) != 0;
  const bool b1 = (l & 2) != 0;
  const float qoff = lo ? 0.f : 0.25f;   // cos(x - 1/4 rev) = sin(x)

  const float es  = esc[0];
  const int hd = l & 3;
  const float dk  = 1.f/(1.f + __expf(-dlg[hd]));
  const float bgl = bg[hd];
  const int crow = (lo ? 0 : 32) + d;
  const f32x4 wg = *(const f32x4*)(Wg + crow*4);

  const int s0   = c*128;
  const int sw   = (c==0) ? 0 : (s0-128);
  const int ng   = (c==0) ? 32 : 64;   // 4-step groups

  const int* idb = ids + b*S_LEN;
  char* chp = (char*)chi + ((size_t)(b*S_LEN + sw)*64 + l)*2;
  char* clp = (char*)clo + ((size_t)(b*S_LEN + sw)*64 + l)*2;

  float h = 0.f, m = 0.f;
  float harr[4];

  const float PHI_F   = 1.6180339887498949f;
  const float TWOPI_F = 6.283185307179586f;
  const float INV2PI  = 0.15915494309189535f;

  auto clampi = [](int x){ return x > (S_LEN-4) ? (S_LEN-4) : x; };

  auto LOADE = [&](const i32x4& q4, float (&wv)[4], float (&bv)[4]){
#pragma unroll
    for (int j=0;j<4;++j){ wv[j] = emb[q4[j]*64 + d]; bv[j] = emb[q4[j]*64 + 32 + d]; }
  };

  // per-lane theta (R3-exact construction + reduction), then angle-sum via reduced
  // revolutions: rsum = rev_r + rev_i (identical rounding in both partner lanes),
  // h_r = cos2pi(rsum), h_i = cos2pi(rsum - 1/4) = sin2pi(rsum).
  auto HSTEP = [&](int s, float wv, float bpv, int j){
    float invw = __builtin_amdgcn_rcpf(1.f + __builtin_fabsf(wv));
    float tp = (float)s * PHI_F;
    float th = __builtin_fmaf(h, invw, bpv) + tp;
    float qf = __builtin_floorf(th * INV2PI);
    float r  = __builtin_fmaf(-qf, TWOPI_F, th);
    r = (r < 0.f) ? (r + TWOPI_F) : r;
    r = (r >= TWOPI_F) ? (r - TWOPI_F) : r;
    float rev = r * INV2PI;            // [0,1)
    float rsum = psum64(rev);          // rev_r + rev_i, [0,2)
    h = cos2pi(fractf_(rsum - qoff));
    harr[j] = h;
  };

  auto GATE = [&](float hv, bool st, char* pc, char* pl){
    float p0 = hv*wg[0], p1 = hv*wg[1], p2 = hv*wg[2], p3 = hv*wg[3];
    // quad fold: after this, mm[l] = sum over quad of p_{l&3}
    float m01 = b0 ? p1 : p0;
    float t01 = b0 ? p0 : p1;
    m01 += dppmov<0xB1>(t01);              // quad_perm xor1
    float m23 = b0 ? p3 : p2;
    float t23 = b0 ? p2 : p3;
    m23 += dppmov<0xB1>(t23);
    float mm = b1 ? m23 : m01;
    float tt = b1 ? m01 : m23;
    mm += dppmov<0x4E>(tt);                // quad_perm xor2
    mm += dppmov<0x124>(mm);               // row_ror:4
    mm += dppmov<0x128>(mm);               // row_ror:8
    mm += swz<0x401F>(mm);                 // xor16 within 32-half
    mm = psum64(mm);                       // cross-32 -> full 64-sum, all lanes
    float g_ = 1.f / (1.f + __expf(-(mm + bgl)));
    m = __builtin_fmaf(dk, m, g_*hv);
    float outv = __builtin_fmaf(es, m, hv);
    unsigned hw_; asm("v_cvt_pk_bf16_f32 %0, %1, %2" : "=v"(hw_) : "v"(outv), "v"(outv));
    float lr_ = outv - __uint_as_float(hw_ << 16);
    unsigned lw_; asm("v_cvt_pk_bf16_f32 %0, %1, %2" : "=v"(lw_) : "v"(lr_), "v"(lr_));
    if (st){ *(ushort*)pc = (ushort)hw_; *(ushort*)pl = (ushort)lw_; }
  };

  float wA[4], bA[4], wB[4], bB[4];

  // prologue: emb for groups 0,1; ids for group 2; h-chain group 0
  i32x4 q0v = *(const i32x4*)(idb + sw);
  LOADE(q0v, wA, bA);
  i32x4 q1v = *(const i32x4*)(idb + clampi(sw + 4));
  LOADE(q1v, wB, bB);
  i32x4 qn = *(const i32x4*)(idb + clampi(sw + 8));
#pragma unroll
  for (int j=0;j<4;++j) HSTEP(sw + j, wA[j], bA[j], j);

  const int ndbl = (ng - 1) >> 1;
  for (int i = 0; i < ndbl; ++i){
    {  // g = 2i+1 : HSTEP from B, prefetch -> A, gate group 2i (from harr)
      int g = 2*i + 1;
      LOADE(qn, wA, bA);
      qn = *(const i32x4*)(idb + clampi(sw + 4*(g+2)));
      int gg = g - 1;
      bool st = (sw + 4*gg) >= s0;
      char* pc = chp + ((size_t)gg << 9);
      char* pl = clp + ((size_t)gg << 9);
      float hs[4] = {harr[0], harr[1], harr[2], harr[3]};
#pragma unroll
      for (int j=0;j<4;++j){
        GATE(hs[j], st, pc + j*128, pl + j*128);
        HSTEP(sw + 4*g + j, wB[j], bB[j], j);
      }
    }
    {  // g = 2i+2 : HSTEP from A, prefetch -> B, gate group 2i+1
      int g = 2*i + 2;
      LOADE(qn, wB, bB);
      qn = *(const i32x4*)(idb + clampi(sw + 4*(g+2)));
      int gg = g - 1;
      bool st = (sw + 4*gg) >= s0;
      char* pc = chp + ((size_t)gg << 9);
      char* pl = clp + ((size_t)gg << 9);
      float hs[4] = {harr[0], harr[1], harr[2], harr[3]};
#pragma unroll
      for (int j=0;j<4;++j){
        GATE(hs[j], st, pc + j*128, pl + j*128);
        HSTEP(sw + 4*g + j, wA[j], bA[j], j);
      }
    }
  }
  {  // leftover g = ng-1 (odd, from B), gate group ng-2
    int g = ng - 1;
    int gg = g - 1;
    bool st = (sw + 4*gg) >= s0;
    char* pc = chp + ((size_t)gg << 9);
    char* pl = clp + ((size_t)gg << 9);
    float hs[4] = {harr[0], harr[1], harr[2], harr[3]};
#pragma unroll
    for (int j=0;j<4;++j){
      GATE(hs[j], st, pc + j*128, pl + j*128);
      HSTEP(sw + 4*g + j, wB[j], bB[j], j);
    }
  }
  {  // epilogue: gate group ng-1
    int gg = ng - 1;
    char* pc = chp + ((size_t)gg << 9);
    char* pl = clp + ((size_t)gg << 9);
#pragma unroll
    for (int j=0;j<4;++j) GATE(harr[j], true, pc + j*128, pl + j*128);
  }
}

// ---------------- projection: [32768,64] x [4096,64]^T, split-bf16 MFMA (unchanged, validated) ----------------
__global__ __launch_bounds__(256) void gemm_kernel(
    const ushort* __restrict__ chi, const ushort* __restrict__ clo,
    const ushort* __restrict__ whi, const ushort* __restrict__ wlo,
    const float* __restrict__ bout, float* __restrict__ out)
{
  __shared__ char lds[65536];  // A_hi | A_lo | W_hi | W_lo, 16KB each
  const int row0 = blockIdx.y * 128;
  const int v0   = blockIdx.x * 128;
  const int t = threadIdx.x;

  {
    const char* s0 = (const char*)(chi) + (size_t)row0 * 128;
    const char* s1 = (const char*)(clo) + (size_t)row0 * 128;
    const char* s2 = (const char*)(whi) + (size_t)v0 * 128;
    const char* s3 = (const char*)(wlo) + (size_t)v0 * 128;
    const char* srcs[4] = {s0, s1, s2, s3};
#pragma unroll
    for (int a2 = 0; a2 < 4; ++a2){
      char* dst = lds + a2 * 16384;
      const char* src = srcs[a2];
#pragma unroll
      for (int i = 0; i < 4; ++i){
        int id = t + 256 * i;          // 1024 chunks of 16B
        int r = id >> 3, ccol = id & 7;
        i32x4 vv = *(const i32x4*)(src + r*128 + ccol*16);
        *(i32x4*)(dst + r*128 + ((ccol ^ (r & 7)) * 16)) = vv;
      }
    }
  }
  __syncthreads();

  const int lane = t & 63;
  const int wid  = t >> 6;
  const int wr = (wid >> 1) * 64;
  const int wc = (wid & 1) * 64;
  const int lr = lane & 15;
  const int lk = lane >> 4;           // k-group 0..3

  f32x4 acc[4][4];
#pragma unroll
  for (int m = 0; m < 4; ++m)
#pragma unroll
    for (int n = 0; n < 4; ++n) acc[m][n] = (f32x4){0.f, 0.f, 0.f, 0.f};

  i32x2 afr[2][4][4];
#pragma unroll
  for (int hf = 0; hf < 2; ++hf){
    const char* Ab = lds + hf * 16384;
#pragma unroll
    for (int m = 0; m < 4; ++m){
      int row = wr + m*16 + lr;
      const char* rp = Ab + row * 128;
      int sw = (row & 7) << 1;
#pragma unroll
      for (int ks = 0; ks < 4; ++ks){
        int c8 = (ks*4 + lk) ^ sw;
        afr[hf][m][ks] = *(const i32x2*)(rp + c8 * 8);
      }
    }
  }
#pragma unroll
  for (int wh = 0; wh < 2; ++wh){
    const char* Bb = lds + 32768 + wh * 16384;
    i32x2 bfr[4][4];
#pragma unroll
    for (int n = 0; n < 4; ++n){
      int row = wc + n*16 + lr;
      const char* rp = Bb + row * 128;
      int sw = (row & 7) << 1;
#pragma unroll
      for (int ks = 0; ks < 4; ++ks){
        int c8 = (ks*4 + lk) ^ sw;
        bfr[n][ks] = *(const i32x2*)(rp + c8 * 8);
      }
    }
#pragma unroll
    for (int hf = 0; hf < 2; ++hf)
#pragma unroll
      for (int m = 0; m < 4; ++m)
#pragma unroll
        for (int n = 0; n < 4; ++n)
#pragma unroll
          for (int ks = 0; ks < 4; ++ks)
            asm("v_mfma_f32_16x16x16_bf16 %0, %1, %2, %0"
                : "+v"(acc[m][n]) : "v"(afr[hf][m][ks]), "v"(bfr[n][ks]));
  }

  // epilogue: C/D layout col = lane&15, row = (lane>>4)*4 + reg
#pragma unroll
  for (int n = 0; n < 4; ++n){
    float bias = bout[v0 + wc + n*16 + lr];
#pragma unroll
    for (int m = 0; m < 4; ++m){
      int gr = row0 + wr + m*16 + lk*4;
      float* op = out + (size_t)gr * 4096 + (v0 + wc + n*16 + lr);
#pragma unroll
      for (int rg = 0; rg < 4; ++rg){
        op[(size_t)rg * 4096] = acc[m][n][rg] + bias;
      }
    }
  }
}

extern "C" void kernel_launch(void* const* d_in, const int* in_sizes, int n_in,
                              void* d_out, int out_size, void* d_ws, size_t ws_size,
                              hipStream_t stream)
{
  const int*   ids  = (const int*)  d_in[0];
  const float* emb  = (const float*)d_in[1];
  const float* Wout = (const float*)d_in[2];
  const float* bout = (const float*)d_in[3];
  const float* Wg   = (const float*)d_in[4];
  const float* bg   = (const float*)d_in[5];
  const float* dlg  = (const float*)d_in[6];
  const float* esc  = (const float*)d_in[7];
  float* out = (float*)d_out;
  char* ws = (char*)d_ws;
  // ws layout: c_hi 4MB | c_lo 4MB | w_hi 512KB | w_lo 512KB  (9MB total)
  ushort* chi = (ushort*)(ws);
  ushort* clo = (ushort*)(ws + 4u*1024u*1024u);
  ushort* whi = (ushort*)(ws + 8u*1024u*1024u);
  ushort* wlo = (ushort*)(ws + 8u*1024u*1024u + 512u*1024u);

  // blocks 0..255: scan; 256..1279: W split (k''-permuted)
  scan_kernel<<<dim3(1280), dim3(64), 0, stream>>>(ids, emb, Wg, bg, dlg, esc,
                                                   chi, clo, Wout, whi, wlo);
  gemm_kernel<<<dim3(32, 256), dim3(256), 0, stream>>>(chi, clo, whi, wlo, bout, out);
}

// Round 9
// 168.836 us; speedup vs baseline: 5.7338x; 1.1277x over previous
//
#include <hip/hip_runtime.h>

#define S_LEN 2048

typedef float f32x4 __attribute__((ext_vector_type(4)));
typedef int   i32x4 __attribute__((ext_vector_type(4)));
typedef int   i32x2 __attribute__((ext_vector_type(2)));

__device__ __forceinline__ float cos2pi(float rev){ float r; asm("v_cos_f32 %0, %1":"=v"(r):"v"(rev)); return r; }
__device__ __forceinline__ float fractf_(float x){ float r; asm("v_fract_f32 %0, %1":"=v"(r):"v"(x)); return r; }
template<int M>
__device__ __forceinline__ float swz(float x){
  return __int_as_float(__builtin_amdgcn_ds_swizzle(__float_as_int(x), M));
}
template<int CTRL>
__device__ __forceinline__ float dppmov(float x){
  return __int_as_float(__builtin_amdgcn_update_dpp(0, __float_as_int(x), CTRL, 0xf, 0xf, false));
}

// lane layout (scan): comp = l>>5 (0:h_r, 1:h_i), d = ((l>>2)&7) | ((l&3)<<3) => head(d) = l&3
// K-permutation: comb element k'' = l  <->  concat index comp*32 + d. W columns permuted identically.

// ================= scan (blocks 0..511) + W-split prep (blocks 512..1535) =================
// 32 chunks x 64 steps, 128-step warm-up (hardware-proven contraction margin: R3/R7 passed
// with WU=128; R8's WU=96 failed via the warm-up tail). Chunks 0-1 are exact (start from
// the true initial state). 3-stage software pipeline per step (audited R8 structure):
//   AF(j): theta->rev, issue shfl(rev)             [ds op 1]
//   G2(j-2): consume psum -> gate, m, store
//   G0(j-1): gate muls + DPP folds, issue swizzle  [ds op 2]
//   AB(j): consume shfl -> h(j)
//   G1(j-1): consume swizzle, issue psum shfl      [ds op 3]
__global__ __launch_bounds__(64) void scan_kernel(
    const int* __restrict__ ids, const float* __restrict__ emb,
    const float* __restrict__ Wg, const float* __restrict__ bg,
    const float* __restrict__ dlg, const float* __restrict__ esc,
    ushort* __restrict__ chi, ushort* __restrict__ clo,
    const float* __restrict__ W32, ushort* __restrict__ whi, ushort* __restrict__ wlo)
{
  const int w = blockIdx.x;
  const int l = threadIdx.x;

  if (w >= 512){
    // ---- W_out -> bf16 hi/lo split with k'' lane permutation (validated R7) ----
    int i0 = (w - 512) * 256 + l * 4;
    int v  = i0 >> 6;
    int q  = (i0 & 63) >> 2;
    int base = v*64 + (q >> 3)*32 + (q & 7);
    float x0 = W32[base], x1 = W32[base+8], x2 = W32[base+16], x3 = W32[base+24];
    unsigned hw01, hw23, lw01, lw23;
    asm("v_cvt_pk_bf16_f32 %0, %1, %2":"=v"(hw01):"v"(x0),"v"(x1));
    asm("v_cvt_pk_bf16_f32 %0, %1, %2":"=v"(hw23):"v"(x2),"v"(x3));
    float r0 = x0 - __uint_as_float(hw01 << 16);
    float r1 = x1 - __uint_as_float(hw01 & 0xffff0000u);
    float r2 = x2 - __uint_as_float(hw23 << 16);
    float r3 = x3 - __uint_as_float(hw23 & 0xffff0000u);
    asm("v_cvt_pk_bf16_f32 %0, %1, %2":"=v"(lw01):"v"(r0),"v"(r1));
    asm("v_cvt_pk_bf16_f32 %0, %1, %2":"=v"(lw23):"v"(r2),"v"(r3));
    *(i32x2*)(whi + i0) = (i32x2){(int)hw01, (int)hw23};
    *(i32x2*)(wlo + i0) = (i32x2){(int)lw01, (int)lw23};
    return;
  }

  const int c  = w >> 4;            // chunk 0..31
  const int b  = w & 15;            // batch
  const bool lo = (l < 32);
  const int d  = ((l >> 2) & 7) | ((l & 3) << 3);
  const bool b0 = (l & 1) != 0;
  const bool b1 = (l & 2) != 0;
  const float qoff = lo ? 0.f : 0.25f;   // cos(x - 1/4 rev) = sin(x)

  const float es  = esc[0];
  const int hd = l & 3;
  const float dk  = 1.f/(1.f + __expf(-dlg[hd]));
  const float bgl = bg[hd];
  const int crow = (lo ? 0 : 32) + d;
  const f32x4 wg = *(const f32x4*)(Wg + crow*4);

  const int s0   = c*64;
  const int sw   = (s0 >= 128) ? (s0 - 128) : 0;
  const int send = s0 + 64;
  const int nq   = (send - sw) >> 2;   // 16 (c=0), 32 (c=1), 48 (c>=2)

  const int* idb = ids + b*S_LEN;
  ushort* pch = chi + (size_t)b*S_LEN*64 + l;
  ushort* pcl = clo + (size_t)b*S_LEN*64 + l;

  const float PHI_F   = 1.6180339887498949f;
  const float TWOPI_F = 6.283185307179586f;
  const float INV2PI  = 0.15915494309189535f;

  float h = 0.f, m = 0.f;
  float h1 = 0.f, h2 = 0.f;     // h(j-1), h(j-2)
  float rev_c, rev_s;           // A pipeline (step j)
  float q0p, swp;               // G0 -> G1 (step j-1)
  float mm1p, psp;              // G1 -> G2 (step j-2)
  float w_[4], b_[4], nw_[4], nb_[4];

  auto clampi = [](int x){ return x > (S_LEN-4) ? (S_LEN-4) : x; };

  auto AF = [&](int s, float wv, float bpv){
    float invw = __builtin_amdgcn_rcpf(1.f + __builtin_fabsf(wv));
    float tp = (float)s * PHI_F;
    float th = __builtin_fmaf(h, invw, bpv) + tp;   // R3-exact order
    float qf = __builtin_floorf(th * INV2PI);
    float r  = __builtin_fmaf(-qf, TWOPI_F, th);
    r = (r < 0.f) ? (r + TWOPI_F) : r;
    r = (r >= TWOPI_F) ? (r - TWOPI_F) : r;
    rev_c = r * INV2PI;                              // [0,1)
    rev_s = __shfl_xor(rev_c, 32, 64);               // issue ds op; consume in AB
  };
  auto AB = [&](){
    float rsum = rev_c + rev_s;                      // identical rounding both halves
    float hn = cos2pi(fractf_(rsum - qoff));         // h_r=cos, h_i=sin via -1/4 rev
    h2 = h1; h1 = hn; h = hn;
  };
  auto G0 = [&](){
    float p0 = h1*wg[0], p1 = h1*wg[1], p2 = h1*wg[2], p3 = h1*wg[3];
    float m01 = b0 ? p1 : p0;
    float t01 = b0 ? p0 : p1;
    m01 += dppmov<0xB1>(t01);              // quad_perm xor1
    float m23 = b0 ? p3 : p2;
    float t23 = b0 ? p2 : p3;
    m23 += dppmov<0xB1>(t23);
    float mm = b1 ? m23 : m01;
    float tt = b1 ? m01 : m23;
    mm += dppmov<0x4E>(tt);                // quad_perm xor2
    mm += dppmov<0x124>(mm);               // row_ror:4
    mm += dppmov<0x128>(mm);               // row_ror:8
    q0p = mm;
    swp = swz<0x401F>(mm);                 // issue ds op; consume in G1
  };
  auto G1 = [&](){
    float mm1 = q0p + swp;
    mm1p = mm1;
    psp = __shfl_xor(mm1, 32, 64);         // issue ds op; consume next body's G2
  };
  auto G2 = [&](int jm2){
    float mm = mm1p + psp;                 // full 64-lane sum, all lanes
    float g_ = 1.f / (1.f + __expf(-(mm + bgl)));
    m = __builtin_fmaf(dk, m, g_*h2);
    float outv = __builtin_fmaf(es, m, h2);
    unsigned hw_; asm("v_cvt_pk_bf16_f32 %0, %1, %2" : "=v"(hw_) : "v"(outv), "v"(outv));
    float lr_ = outv - __uint_as_float(hw_ << 16);
    unsigned lw_; asm("v_cvt_pk_bf16_f32 %0, %1, %2" : "=v"(lw_) : "v"(lr_), "v"(lr_));
    if (jm2 >= s0){ pch[jm2*64] = (ushort)hw_; pcl[jm2*64] = (ushort)lw_; }
  };

  // ---- prologue: emb group0 -> w_, group1 -> nw_, ids group2 -> qn ----
  {
    i32x4 q0v = *(const i32x4*)(idb + sw);
#pragma unroll
    for (int k=0;k<4;++k){ w_[k] = emb[q0v[k]*64 + d]; b_[k] = emb[q0v[k]*64 + 32 + d]; }
  }
  {
    i32x4 q1v = *(const i32x4*)(idb + clampi(sw + 4));
#pragma unroll
    for (int k=0;k<4;++k){ nw_[k] = emb[q1v[k]*64 + d]; nb_[k] = emb[q1v[k]*64 + 32 + d]; }
  }
  i32x4 qn = *(const i32x4*)(idb + clampi(sw + 8));

  // pipeline fill: body(sw), body(sw+1)
  AF(sw,   w_[0], b_[0]); AB();
  AF(sw+1, w_[1], b_[1]); G0(); AB(); G1();

  // main: bodies j = sw+2 .. send-1 in quads of phases {2,3,0,1}; boundary at phase 0
  for (int i = 0; i < nq-1; ++i){
    int j0 = sw + 2 + 4*i;
    AF(j0,   w_[2], b_[2]); G2(j0-2); G0(); AB(); G1();
    AF(j0+1, w_[3], b_[3]); G2(j0-1); G0(); AB(); G1();
    // group boundary: rotate emb ring, issue next group's loads
#pragma unroll
    for (int k=0;k<4;++k){ w_[k] = nw_[k]; b_[k] = nb_[k]; }
    {
      i32x4 qq = qn;
#pragma unroll
      for (int k=0;k<4;++k){ nw_[k] = emb[qq[k]*64 + d]; nb_[k] = emb[qq[k]*64 + 32 + d]; }
      qn = *(const i32x4*)(idb + clampi(sw + 4*(i+3)));
    }
    AF(j0+2, w_[0], b_[0]); G2(j0);   G0(); AB(); G1();
    AF(j0+3, w_[1], b_[1]); G2(j0+1); G0(); AB(); G1();
  }
  // tail bodies: phases 2,3 of last group
  AF(send-2, w_[2], b_[2]); G2(send-4); G0(); AB(); G1();
  AF(send-1, w_[3], b_[3]); G2(send-3); G0(); AB(); G1();
  // drain
  G2(send-2);
  G0(); G1();
  h2 = h1;
  G2(send-1);
}

// ---------------- projection: [32768,64] x [4096,64]^T, split-bf16 MFMA (unchanged, validated) ----------------
__global__ __launch_bounds__(256) void gemm_kernel(
    const ushort* __restrict__ chi, const ushort* __restrict__ clo,
    const ushort* __restrict__ whi, const ushort* __restrict__ wlo,
    const float* __restrict__ bout, float* __restrict__ out)
{
  __shared__ char lds[65536];  // A_hi | A_lo | W_hi | W_lo, 16KB each
  const int row0 = blockIdx.y * 128;
  const int v0   = blockIdx.x * 128;
  const int t = threadIdx.x;

  {
    const char* s0 = (const char*)(chi) + (size_t)row0 * 128;
    const char* s1 = (const char*)(clo) + (size_t)row0 * 128;
    const char* s2 = (const char*)(whi) + (size_t)v0 * 128;
    const char* s3 = (const char*)(wlo) + (size_t)v0 * 128;
    const char* srcs[4] = {s0, s1, s2, s3};
#pragma unroll
    for (int a2 = 0; a2 < 4; ++a2){
      char* dst = lds + a2 * 16384;
      const char* src = srcs[a2];
#pragma unroll
      for (int i = 0; i < 4; ++i){
        int id = t + 256 * i;          // 1024 chunks of 16B
        int r = id >> 3, ccol = id & 7;
        i32x4 vv = *(const i32x4*)(src + r*128 + ccol*16);
        *(i32x4*)(dst + r*128 + ((ccol ^ (r & 7)) * 16)) = vv;
      }
    }
  }
  __syncthreads();

  const int lane = t & 63;
  const int wid  = t >> 6;
  const int wr = (wid >> 1) * 64;
  const int wc = (wid & 1) * 64;
  const int lr = lane & 15;
  const int lk = lane >> 4;           // k-group 0..3

  f32x4 acc[4][4];
#pragma unroll
  for (int m = 0; m < 4; ++m)
#pragma unroll
    for (int n = 0; n < 4; ++n) acc[m][n] = (f32x4){0.f, 0.f, 0.f, 0.f};

  i32x2 afr[2][4][4];
#pragma unroll
  for (int hf = 0; hf < 2; ++hf){
    const char* Ab = lds + hf * 16384;
#pragma unroll
    for (int m = 0; m < 4; ++m){
      int row = wr + m*16 + lr;
      const char* rp = Ab + row * 128;
      int sw = (row & 7) << 1;
#pragma unroll
      for (int ks = 0; ks < 4; ++ks){
        int c8 = (ks*4 + lk) ^ sw;
        afr[hf][m][ks] = *(const i32x2*)(rp + c8 * 8);
      }
    }
  }
#pragma unroll
  for (int wh = 0; wh < 2; ++wh){
    const char* Bb = lds + 32768 + wh * 16384;
    i32x2 bfr[4][4];
#pragma unroll
    for (int n = 0; n < 4; ++n){
      int row = wc + n*16 + lr;
      const char* rp = Bb + row * 128;
      int sw = (row & 7) << 1;
#pragma unroll
      for (int ks = 0; ks < 4; ++ks){
        int c8 = (ks*4 + lk) ^ sw;
        bfr[n][ks] = *(const i32x2*)(rp + c8 * 8);
      }
    }
#pragma unroll
    for (int hf = 0; hf < 2; ++hf)
#pragma unroll
      for (int m = 0; m < 4; ++m)
#pragma unroll
        for (int n = 0; n < 4; ++n)
#pragma unroll
          for (int ks = 0; ks < 4; ++ks)
            asm("v_mfma_f32_16x16x16_bf16 %0, %1, %2, %0"
                : "+v"(acc[m][n]) : "v"(afr[hf][m][ks]), "v"(bfr[n][ks]));
  }

  // epilogue: C/D layout col = lane&15, row = (lane>>4)*4 + reg
#pragma unroll
  for (int n = 0; n < 4; ++n){
    float bias = bout[v0 + wc + n*16 + lr];
#pragma unroll
    for (int m = 0; m < 4; ++m){
      int gr = row0 + wr + m*16 + lk*4;
      float* op = out + (size_t)gr * 4096 + (v0 + wc + n*16 + lr);
#pragma unroll
      for (int rg = 0; rg < 4; ++rg){
        op[(size_t)rg * 4096] = acc[m][n][rg] + bias;
      }
    }
  }
}

extern "C" void kernel_launch(void* const* d_in, const int* in_sizes, int n_in,
                              void* d_out, int out_size, void* d_ws, size_t ws_size,
                              hipStream_t stream)
{
  const int*   ids  = (const int*)  d_in[0];
  const float* emb  = (const float*)d_in[1];
  const float* Wout = (const float*)d_in[2];
  const float* bout = (const float*)d_in[3];
  const float* Wg   = (const float*)d_in[4];
  const float* bg   = (const float*)d_in[5];
  const float* dlg  = (const float*)d_in[6];
  const float* esc  = (const float*)d_in[7];
  float* out = (float*)d_out;
  char* ws = (char*)d_ws;
  // ws layout: c_hi 4MB | c_lo 4MB | w_hi 512KB | w_lo 512KB  (9MB total)
  ushort* chi = (ushort*)(ws);
  ushort* clo = (ushort*)(ws + 4u*1024u*1024u);
  ushort* whi = (ushort*)(ws + 8u*1024u*1024u);
  ushort* wlo = (ushort*)(ws + 8u*1024u*1024u + 512u*1024u);

  // blocks 0..511: scan (32 chunks x 16 batches); 512..1535: W split (k''-permuted)
  scan_kernel<<<dim3(1536), dim3(64), 0, stream>>>(ids, emb, Wg, bg, dlg, esc,
                                                   chi, clo, Wout, whi, wlo);
  gemm_kernel<<<dim3(32, 256), dim3(256), 0, stream>>>(chi, clo, whi, wlo, bout, out);
}